// Round 2
// baseline (625.085 us; speedup 1.0000x reference)
//
#include <hip/hip_runtime.h>
#include <cstdint>
#include <cstddef>

#define N_NODES 100000
#define N_EDGES 800000
#define IN_DIM 128
#define HID_DIM 256
#define OUT_DIM 128

// ---------------------------------------------------------------------------
// Degree (weighted) + in-edge count histogram.
// NOTE: edge_index arrives as int32 (harness converts all integer inputs).
// ---------------------------------------------------------------------------
__global__ void deg_count_kernel(const int* __restrict__ ei,
                                 const float* __restrict__ ew,
                                 float* __restrict__ deg,
                                 int* __restrict__ cnt) {
    int e = blockIdx.x * 256 + threadIdx.x;
    if (e >= N_EDGES) return;
    int c = ei[N_EDGES + e];   // target
    atomicAdd(&deg[c], ew[e]);
    atomicAdd(&cnt[c], 1);
}

__global__ void dis_kernel(const float* __restrict__ deg, float* __restrict__ dis) {
    int i = blockIdx.x * 256 + threadIdx.x;
    if (i >= N_NODES) return;
    float d = deg[i];
    dis[i] = d > 0.f ? rsqrtf(d) : 0.f;
}

// ---------------------------------------------------------------------------
// 3-kernel exclusive scan (counts -> row_ptr), 256/block
// ---------------------------------------------------------------------------
__global__ void scan1_kernel(const int* __restrict__ in, int* __restrict__ out,
                             int* __restrict__ bsums, int n) {
    __shared__ int tmp[256];
    int t = threadIdx.x;
    int i = blockIdx.x * 256 + t;
    int v = (i < n) ? in[i] : 0;
    tmp[t] = v;
    __syncthreads();
    for (int off = 1; off < 256; off <<= 1) {
        int u = (t >= off) ? tmp[t - off] : 0;
        __syncthreads();
        tmp[t] += u;
        __syncthreads();
    }
    if (i < n) out[i] = tmp[t] - v;          // exclusive
    if (t == 255) bsums[blockIdx.x] = tmp[255];
}

__global__ void scan2_kernel(int* __restrict__ bsums, int nb) {
    __shared__ int tmp[512];
    int t = threadIdx.x;
    int v = (t < nb) ? bsums[t] : 0;
    tmp[t] = v;
    __syncthreads();
    for (int off = 1; off < 512; off <<= 1) {
        int u = (t >= off) ? tmp[t - off] : 0;
        __syncthreads();
        tmp[t] += u;
        __syncthreads();
    }
    if (t < nb) bsums[t] = tmp[t] - v;       // exclusive
}

__global__ void scan3_kernel(int* __restrict__ row_ptr, const int* __restrict__ bsums,
                             int* __restrict__ cursor, int n, int total) {
    int i = blockIdx.x * 256 + threadIdx.x;
    if (i == 0) row_ptr[n] = total;
    if (i >= n) return;
    int v = row_ptr[i] + bsums[blockIdx.x];
    row_ptr[i] = v;
    cursor[i] = v;
}

// ---------------------------------------------------------------------------
// CSR fill: edge e -> slot at its target node; precompute norm
// ---------------------------------------------------------------------------
__global__ void fill_kernel(const int* __restrict__ ei,
                            const float* __restrict__ ew,
                            const float* __restrict__ dis,
                            int* __restrict__ cursor,
                            int* __restrict__ srcs,
                            float* __restrict__ nrm) {
    int e = blockIdx.x * 256 + threadIdx.x;
    if (e >= N_EDGES) return;
    int r = ei[e];
    int c = ei[N_EDGES + e];
    int pos = atomicAdd(&cursor[c], 1);
    srcs[pos] = r;
    nrm[pos] = dis[r] * ew[e] * dis[c];
}

// ---------------------------------------------------------------------------
// Aggregation: one wave per node, 128 feature dims (float2 per lane).
// out[v] = sum_{e in CSR[v]} nrm[e] * feat[src[e]]  (+ optional bias)
// ---------------------------------------------------------------------------
__global__ void aggregate_kernel(const float* __restrict__ feat,
                                 const int* __restrict__ row_ptr,
                                 const int* __restrict__ srcs,
                                 const float* __restrict__ nrm,
                                 float* __restrict__ out,
                                 const float* __restrict__ bias) {
    int gtid = blockIdx.x * blockDim.x + threadIdx.x;
    int wave = gtid >> 6;
    int lane = threadIdx.x & 63;
    if (wave >= N_NODES) return;
    int beg = row_ptr[wave];
    int end = row_ptr[wave + 1];
    float2 acc = make_float2(0.f, 0.f);
    for (int j = beg; j < end; ++j) {
        int s = srcs[j];
        float w = nrm[j];
        float2 v = *(const float2*)(feat + (size_t)s * 128 + lane * 2);
        acc.x += w * v.x;
        acc.y += w * v.y;
    }
    if (bias) {
        float2 b = *(const float2*)(bias + lane * 2);
        acc.x += b.x;
        acc.y += b.y;
    }
    *(float2*)(out + (size_t)wave * 128 + lane * 2) = acc;
}

// ---------------------------------------------------------------------------
// fp32 tiled GEMM: C[M,NC] = A[M,K] @ W[K,NC] (+bias) (optional relu)
// BM=64 BN=64 BK=32, 256 threads, 4x4 micro-tile.
// ---------------------------------------------------------------------------
template <int K, int NC>
__global__ __launch_bounds__(256) void gemm_kernel(const float* __restrict__ A,
                                                   const float* __restrict__ W,
                                                   const float* __restrict__ bias,
                                                   float* __restrict__ C,
                                                   int M, int do_relu) {
    constexpr int BM = 64, BN = 64, BK = 32;
    __shared__ float As[BK][BM + 4];   // stride 68 floats (16B-aligned rows)
    __shared__ float Ws[BK][BN + 4];
    int t = threadIdx.x;
    int m0 = blockIdx.x * BM;
    int n0 = blockIdx.y * BN;
    int tx = t & 15, ty = t >> 4;
    float acc[4][4] = {};

    for (int k0 = 0; k0 < K; k0 += BK) {
        // A tile: 64 rows x 32 k = 512 float4, transposed into As[k][m]
        #pragma unroll
        for (int i = 0; i < 2; ++i) {
            int idx = t + i * 256;
            int m = idx >> 3;
            int kq = idx & 7;
            float4 a = make_float4(0.f, 0.f, 0.f, 0.f);
            if (m0 + m < M)
                a = *(const float4*)(A + (size_t)(m0 + m) * K + k0 + kq * 4);
            As[kq * 4 + 0][m] = a.x;
            As[kq * 4 + 1][m] = a.y;
            As[kq * 4 + 2][m] = a.z;
            As[kq * 4 + 3][m] = a.w;
        }
        // W tile: 32 k x 64 n = 512 float4, direct
        #pragma unroll
        for (int i = 0; i < 2; ++i) {
            int idx = t + i * 256;
            int kk = idx >> 4;
            int nq = idx & 15;
            *(float4*)&Ws[kk][nq * 4] =
                *(const float4*)(W + (size_t)(k0 + kk) * NC + n0 + nq * 4);
        }
        __syncthreads();
        #pragma unroll
        for (int kk = 0; kk < BK; ++kk) {
            float4 a = *(const float4*)&As[kk][tx * 4];
            float4 w = *(const float4*)&Ws[kk][ty * 4];
            float av[4] = {a.x, a.y, a.z, a.w};
            float wv[4] = {w.x, w.y, w.z, w.w};
            #pragma unroll
            for (int i = 0; i < 4; ++i)
                #pragma unroll
                for (int j = 0; j < 4; ++j)
                    acc[i][j] += av[i] * wv[j];
        }
        __syncthreads();
    }

    #pragma unroll
    for (int i = 0; i < 4; ++i) {
        int row = m0 + tx * 4 + i;
        if (row >= M) continue;
        #pragma unroll
        for (int j = 0; j < 4; ++j) {
            int col = n0 + ty * 4 + j;
            float v = acc[i][j] + (bias ? bias[col] : 0.f);
            if (do_relu) v = fmaxf(v, 0.f);
            C[(size_t)row * NC + col] = v;
        }
    }
}

// ---------------------------------------------------------------------------
extern "C" void kernel_launch(void* const* d_in, const int* in_sizes, int n_in,
                              void* d_out, int out_size, void* d_ws, size_t ws_size,
                              hipStream_t stream) {
    const float* x  = (const float*)d_in[0];
    const int*   ei = (const int*)d_in[1];    // int32! harness converts integer inputs
    const float* ew = (const float*)d_in[2];
    const float* W1 = (const float*)d_in[3];
    const float* b1 = (const float*)d_in[4];
    const float* W2 = (const float*)d_in[5];
    const float* b2 = (const float*)d_in[6];
    float* out = (float*)d_out;

    char* ws = (char*)d_ws;
    size_t off = 0;
    auto alloc = [&](size_t bytes) -> void* {
        void* p = ws + off;
        off = (off + bytes + 255) & ~(size_t)255;
        return p;
    };
    float* deg    = (float*)alloc((size_t)N_NODES * 4);
    int*   cnt    = (int*)  alloc((size_t)N_NODES * 4);
    float* dis    = (float*)alloc((size_t)N_NODES * 4);
    int*   rowp   = (int*)  alloc((size_t)(N_NODES + 1) * 4);
    int*   cursor = (int*)  alloc((size_t)N_NODES * 4);
    int*   bsums  = (int*)  alloc(512 * 4);
    int*   srcs   = (int*)  alloc((size_t)N_EDGES * 4);
    float* nrm    = (float*)alloc((size_t)N_EDGES * 4);
    float* A1     = (float*)alloc((size_t)N_NODES * IN_DIM * 4);   // reused as t
    float* h1     = (float*)alloc((size_t)N_NODES * HID_DIM * 4);

    // zero deg + cnt (they are adjacent in ws)
    size_t zbytes = (size_t)((char*)cnt - (char*)deg) + (size_t)N_NODES * 4;
    hipMemsetAsync(deg, 0, zbytes, stream);

    int ne_blocks = (N_EDGES + 255) / 256;
    int nn_blocks = (N_NODES + 255) / 256;   // 391

    deg_count_kernel<<<ne_blocks, 256, 0, stream>>>(ei, ew, deg, cnt);
    dis_kernel<<<nn_blocks, 256, 0, stream>>>(deg, dis);
    scan1_kernel<<<nn_blocks, 256, 0, stream>>>(cnt, rowp, bsums, N_NODES);
    scan2_kernel<<<1, 512, 0, stream>>>(bsums, nn_blocks);
    scan3_kernel<<<nn_blocks, 256, 0, stream>>>(rowp, bsums, cursor, N_NODES, N_EDGES);
    fill_kernel<<<ne_blocks, 256, 0, stream>>>(ei, ew, dis, cursor, srcs, nrm);

    // layer 1: aggregate x (128) -> A1, then h1 = relu(A1 @ W1 + b1)
    aggregate_kernel<<<(N_NODES + 3) / 4, 256, 0, stream>>>(x, rowp, srcs, nrm, A1, nullptr);
    dim3 g1((N_NODES + 63) / 64, HID_DIM / 64);
    gemm_kernel<IN_DIM, HID_DIM><<<g1, 256, 0, stream>>>(A1, W1, b1, h1, N_NODES, 1);

    // layer 2: t = h1 @ W2 (128 wide), then out = aggregate(t) + b2
    float* t = A1;
    dim3 g2((N_NODES + 63) / 64, OUT_DIM / 64);
    gemm_kernel<HID_DIM, OUT_DIM><<<g2, 256, 0, stream>>>(h1, W2, nullptr, t, N_NODES, 0);
    aggregate_kernel<<<(N_NODES + 3) / 4, 256, 0, stream>>>(t, rowp, srcs, nrm, out, b2);
}

// Round 3
// 412.027 us; speedup vs baseline: 1.5171x; 1.5171x over previous
//
#include <hip/hip_runtime.h>
#include <hip/hip_bf16.h>
#include <cstdint>
#include <cstddef>

#define N_NODES 100000
#define N_EDGES 800000
#define IN_DIM 128
#define HID_DIM 256
#define OUT_DIM 128

typedef __attribute__((ext_vector_type(8))) short bf16x8;
typedef __attribute__((ext_vector_type(4))) float f32x4;

__device__ __forceinline__ unsigned short f32_to_bf16(float f) {
    __hip_bfloat16 b = __float2bfloat16(f);   // RNE
    return *reinterpret_cast<unsigned short*>(&b);
}
__device__ __forceinline__ float bf16_lo(uint32_t u) { // low ushort -> float
    uint32_t v = u << 16; return *reinterpret_cast<float*>(&v);
}
__device__ __forceinline__ float bf16_hi(uint32_t u) {
    uint32_t v = u & 0xffff0000u; return *reinterpret_cast<float*>(&v);
}

// ---------------------------------------------------------------------------
// CSR build (edge_index arrives as int32: harness converts integer inputs)
// ---------------------------------------------------------------------------
__global__ void deg_count_kernel(const int* __restrict__ ei,
                                 const float* __restrict__ ew,
                                 float* __restrict__ deg,
                                 int* __restrict__ cnt) {
    int e = blockIdx.x * 256 + threadIdx.x;
    if (e >= N_EDGES) return;
    int c = ei[N_EDGES + e];   // target
    atomicAdd(&deg[c], ew[e]);
    atomicAdd(&cnt[c], 1);
}

__global__ void dis_kernel(const float* __restrict__ deg, float* __restrict__ dis) {
    int i = blockIdx.x * 256 + threadIdx.x;
    if (i >= N_NODES) return;
    float d = deg[i];
    dis[i] = d > 0.f ? rsqrtf(d) : 0.f;
}

__global__ void scan1_kernel(const int* __restrict__ in, int* __restrict__ out,
                             int* __restrict__ bsums, int n) {
    __shared__ int tmp[256];
    int t = threadIdx.x;
    int i = blockIdx.x * 256 + t;
    int v = (i < n) ? in[i] : 0;
    tmp[t] = v;
    __syncthreads();
    for (int off = 1; off < 256; off <<= 1) {
        int u = (t >= off) ? tmp[t - off] : 0;
        __syncthreads();
        tmp[t] += u;
        __syncthreads();
    }
    if (i < n) out[i] = tmp[t] - v;          // exclusive
    if (t == 255) bsums[blockIdx.x] = tmp[255];
}

__global__ void scan2_kernel(int* __restrict__ bsums, int nb) {
    __shared__ int tmp[512];
    int t = threadIdx.x;
    int v = (t < nb) ? bsums[t] : 0;
    tmp[t] = v;
    __syncthreads();
    for (int off = 1; off < 512; off <<= 1) {
        int u = (t >= off) ? tmp[t - off] : 0;
        __syncthreads();
        tmp[t] += u;
        __syncthreads();
    }
    if (t < nb) bsums[t] = tmp[t] - v;       // exclusive
}

__global__ void scan3_kernel(int* __restrict__ row_ptr, const int* __restrict__ bsums,
                             int* __restrict__ cursor, int n, int total) {
    int i = blockIdx.x * 256 + threadIdx.x;
    if (i == 0) row_ptr[n] = total;
    if (i >= n) return;
    int v = row_ptr[i] + bsums[blockIdx.x];
    row_ptr[i] = v;
    cursor[i] = v;
}

__global__ void fill_kernel(const int* __restrict__ ei,
                            const float* __restrict__ ew,
                            const float* __restrict__ dis,
                            int* __restrict__ cursor,
                            int* __restrict__ srcs,
                            float* __restrict__ nrm) {
    int e = blockIdx.x * 256 + threadIdx.x;
    if (e >= N_EDGES) return;
    int r = ei[e];
    int c = ei[N_EDGES + e];
    int pos = atomicAdd(&cursor[c], 1);
    srcs[pos] = r;
    nrm[pos] = dis[r] * ew[e] * dis[c];
}

// ---------------------------------------------------------------------------
// Weight transpose + cast: in fp32 [R][C] -> out bf16 [C][R]
// ---------------------------------------------------------------------------
__global__ void transpose_cast_kernel(const float* __restrict__ in,
                                      unsigned short* __restrict__ out,
                                      int R, int C) {
    int idx = blockIdx.x * 256 + threadIdx.x;
    if (idx >= R * C) return;
    int r = idx / C, c = idx % C;
    out[(size_t)c * R + r] = f32_to_bf16(in[idx]);
}

// ---------------------------------------------------------------------------
// Aggregation: one wave per node, 128 dims (2/lane). 4x edge unroll for MLP.
// TIN/TOUT in {float, bf16(as ushort)}.
// ---------------------------------------------------------------------------
template <bool IN_BF16, bool OUT_BF16>
__global__ void aggregate_kernel(const void* __restrict__ feat_v,
                                 const int* __restrict__ row_ptr,
                                 const int* __restrict__ srcs,
                                 const float* __restrict__ nrm,
                                 void* __restrict__ out_v,
                                 const float* __restrict__ bias) {
    int gtid = blockIdx.x * blockDim.x + threadIdx.x;
    int node = gtid >> 6;
    int lane = threadIdx.x & 63;
    if (node >= N_NODES) return;
    int beg = row_ptr[node];
    int end = row_ptr[node + 1];
    float ax = 0.f, ay = 0.f;

    auto gather = [&](int s, float& vx, float& vy) {
        if (IN_BF16) {
            const uint32_t* f = (const uint32_t*)feat_v;
            uint32_t u = f[(size_t)s * 64 + lane];
            vx = bf16_lo(u); vy = bf16_hi(u);
        } else {
            const float2* f = (const float2*)feat_v;
            float2 v = f[(size_t)s * 64 + lane];
            vx = v.x; vy = v.y;
        }
    };

    int j = beg;
    for (; j + 4 <= end; j += 4) {
        int s0 = srcs[j], s1 = srcs[j + 1], s2 = srcs[j + 2], s3 = srcs[j + 3];
        float w0 = nrm[j], w1 = nrm[j + 1], w2 = nrm[j + 2], w3 = nrm[j + 3];
        float x0, y0, x1, y1, x2, y2, x3, y3;
        gather(s0, x0, y0); gather(s1, x1, y1);
        gather(s2, x2, y2); gather(s3, x3, y3);
        ax += w0 * x0 + w1 * x1 + w2 * x2 + w3 * x3;
        ay += w0 * y0 + w1 * y1 + w2 * y2 + w3 * y3;
    }
    for (; j < end; ++j) {
        float vx, vy;
        gather(srcs[j], vx, vy);
        float w = nrm[j];
        ax += w * vx; ay += w * vy;
    }
    if (bias) {
        float2 b = *(const float2*)(bias + lane * 2);
        ax += b.x; ay += b.y;
    }
    if (OUT_BF16) {
        uint32_t p = (uint32_t)f32_to_bf16(ax) | ((uint32_t)f32_to_bf16(ay) << 16);
        ((uint32_t*)out_v)[(size_t)node * 64 + lane] = p;
    } else {
        ((float2*)out_v)[(size_t)node * 64 + lane] = make_float2(ax, ay);
    }
}

// ---------------------------------------------------------------------------
// bf16 MFMA GEMM: C[M,NC] = A[M,K] @ BT[NC,K]^T (+bias, optional relu), C bf16.
// BM=BN=128, BK=32, 256 threads (4 waves, each 64x64), global_load_lds width 16.
// ---------------------------------------------------------------------------
template <int K, int NC, bool RELU>
__global__ __launch_bounds__(256) void gemm_bf16(const unsigned short* __restrict__ A,
                                                 const unsigned short* __restrict__ BT,
                                                 const float* __restrict__ bias,
                                                 unsigned short* __restrict__ C,
                                                 int M) {
    constexpr int BM = 128, BN = 128, BK = 32;
    __shared__ unsigned short As[BM * BK];   // row-major [m][k], 8KB
    __shared__ unsigned short Bs[BN * BK];   // row-major [n][k], 8KB
    int tid = threadIdx.x;
    int wave = tid >> 6, lane = tid & 63;
    int m0 = blockIdx.x * BM, n0 = blockIdx.y * BN;
    int wr = (wave & 1) * 64, wc = (wave >> 1) * 64;
    int fr = lane & 15, fq = lane >> 4;

    f32x4 acc[4][4] = {};

    for (int k0 = 0; k0 < K; k0 += BK) {
        // stage A and B tiles: chunk c = 16B = 8 bf16; row = c>>2, q = c&3.
        // LDS dest is wave-uniform base + lane*16 -> layout stays exactly linear.
        #pragma unroll
        for (int i = 0; i < 2; ++i) {
            int cbase = (i * 4 + wave) * 64;          // first chunk of this issue
            int c = cbase + lane;
            int m = c >> 2, q = c & 3;
            int gm = m0 + m; if (gm >= M) gm = M - 1; // clamp; rows>=M unguarded but unstored
            const unsigned short* ga = A + (size_t)gm * K + k0 + q * 8;
            __builtin_amdgcn_global_load_lds(
                (const __attribute__((address_space(1))) void*)ga,
                (__attribute__((address_space(3))) void*)(As + (size_t)cbase * 8),
                16, 0, 0);
            const unsigned short* gb = BT + (size_t)(n0 + m) * K + k0 + q * 8;
            __builtin_amdgcn_global_load_lds(
                (const __attribute__((address_space(1))) void*)gb,
                (__attribute__((address_space(3))) void*)(Bs + (size_t)cbase * 8),
                16, 0, 0);
        }
        __syncthreads();

        bf16x8 af[4], bfr[4];
        #pragma unroll
        for (int mt = 0; mt < 4; ++mt)
            af[mt] = *(const bf16x8*)(As + (wr + mt * 16 + fr) * BK + fq * 8);
        #pragma unroll
        for (int nt = 0; nt < 4; ++nt)
            bfr[nt] = *(const bf16x8*)(Bs + (wc + nt * 16 + fr) * BK + fq * 8);
        #pragma unroll
        for (int mt = 0; mt < 4; ++mt)
            #pragma unroll
            for (int nt = 0; nt < 4; ++nt)
                acc[mt][nt] = __builtin_amdgcn_mfma_f32_16x16x32_bf16(
                    af[mt], bfr[nt], acc[mt][nt], 0, 0, 0);
        __syncthreads();
    }

    // epilogue: C/D layout col=lane&15, row=(lane>>4)*4+reg (m89-verified)
    #pragma unroll
    for (int mt = 0; mt < 4; ++mt) {
        #pragma unroll
        for (int r = 0; r < 4; ++r) {
            int row = m0 + wr + mt * 16 + fq * 4 + r;
            if (row >= M) continue;
            #pragma unroll
            for (int nt = 0; nt < 4; ++nt) {
                int col = n0 + wc + nt * 16 + fr;
                float v = acc[mt][nt][r];
                if (bias) v += bias[col];
                if (RELU) v = fmaxf(v, 0.f);
                C[(size_t)row * NC + col] = f32_to_bf16(v);
            }
        }
    }
}

// ---------------------------------------------------------------------------
extern "C" void kernel_launch(void* const* d_in, const int* in_sizes, int n_in,
                              void* d_out, int out_size, void* d_ws, size_t ws_size,
                              hipStream_t stream) {
    const float* x  = (const float*)d_in[0];
    const int*   ei = (const int*)d_in[1];    // int32 (harness converts ints)
    const float* ew = (const float*)d_in[2];
    const float* W1 = (const float*)d_in[3];
    const float* b1 = (const float*)d_in[4];
    const float* W2 = (const float*)d_in[5];
    const float* b2 = (const float*)d_in[6];
    float* out = (float*)d_out;

    char* ws = (char*)d_ws;
    size_t off = 0;
    auto alloc = [&](size_t bytes) -> void* {
        void* p = ws + off;
        off = (off + bytes + 255) & ~(size_t)255;
        return p;
    };
    float* deg    = (float*)alloc((size_t)N_NODES * 4);
    int*   cnt    = (int*)  alloc((size_t)N_NODES * 4);
    float* dis    = (float*)alloc((size_t)N_NODES * 4);
    int*   rowp   = (int*)  alloc((size_t)(N_NODES + 1) * 4);
    int*   cursor = (int*)  alloc((size_t)N_NODES * 4);
    int*   bsums  = (int*)  alloc(512 * 4);
    int*   srcs   = (int*)  alloc((size_t)N_EDGES * 4);
    float* nrm    = (float*)alloc((size_t)N_EDGES * 4);
    unsigned short* W1T = (unsigned short*)alloc((size_t)IN_DIM * HID_DIM * 2);   // [256][128]
    unsigned short* W2T = (unsigned short*)alloc((size_t)HID_DIM * OUT_DIM * 2);  // [128][256]
    unsigned short* A1  = (unsigned short*)alloc((size_t)N_NODES * IN_DIM * 2);   // agg1 out / t
    unsigned short* h1  = (unsigned short*)alloc((size_t)N_NODES * HID_DIM * 2);

    // zero deg + cnt (adjacent in ws)
    size_t zbytes = (size_t)((char*)cnt - (char*)deg) + (size_t)N_NODES * 4;
    hipMemsetAsync(deg, 0, zbytes, stream);

    int ne_blocks = (N_EDGES + 255) / 256;
    int nn_blocks = (N_NODES + 255) / 256;   // 391

    deg_count_kernel<<<ne_blocks, 256, 0, stream>>>(ei, ew, deg, cnt);
    dis_kernel<<<nn_blocks, 256, 0, stream>>>(deg, dis);
    scan1_kernel<<<nn_blocks, 256, 0, stream>>>(cnt, rowp, bsums, N_NODES);
    scan2_kernel<<<1, 512, 0, stream>>>(bsums, nn_blocks);
    scan3_kernel<<<nn_blocks, 256, 0, stream>>>(rowp, bsums, cursor, N_NODES, N_EDGES);
    fill_kernel<<<ne_blocks, 256, 0, stream>>>(ei, ew, dis, cursor, srcs, nrm);

    transpose_cast_kernel<<<(IN_DIM * HID_DIM + 255) / 256, 256, 0, stream>>>(W1, W1T, IN_DIM, HID_DIM);
    transpose_cast_kernel<<<(HID_DIM * OUT_DIM + 255) / 256, 256, 0, stream>>>(W2, W2T, HID_DIM, OUT_DIM);

    int agg_blocks = (N_NODES + 3) / 4;      // 4 waves/block, 1 node/wave

    // layer 1: A1 = agg(x) [bf16], h1 = relu(A1 @ W1 + b1) [bf16]
    aggregate_kernel<false, true><<<agg_blocks, 256, 0, stream>>>(x, rowp, srcs, nrm, A1, nullptr);
    dim3 g1((N_NODES + 127) / 128, HID_DIM / 128);
    gemm_bf16<IN_DIM, HID_DIM, true><<<g1, 256, 0, stream>>>(A1, W1T, b1, h1, N_NODES);

    // layer 2: t = h1 @ W2 [bf16], out = agg(t) + b2 [fp32]
    unsigned short* t = A1;
    dim3 g2((N_NODES + 127) / 128, OUT_DIM / 128);
    gemm_bf16<HID_DIM, OUT_DIM, false><<<g2, 256, 0, stream>>>(h1, W2T, nullptr, t, N_NODES);
    aggregate_kernel<true, false><<<agg_blocks, 256, 0, stream>>>(t, rowp, srcs, nrm, out, b2);
}

// Round 4
// 368.804 us; speedup vs baseline: 1.6949x; 1.1172x over previous
//
#include <hip/hip_runtime.h>
#include <hip/hip_bf16.h>
#include <cstdint>
#include <cstddef>

#define N_NODES 100000
#define N_EDGES 800000
#define IN_DIM 128
#define HID_DIM 256
#define OUT_DIM 128

typedef __attribute__((ext_vector_type(8))) short bf16x8;
typedef __attribute__((ext_vector_type(4))) float f32x4;

__device__ __forceinline__ unsigned short f32_to_bf16(float f) {
    __hip_bfloat16 b = __float2bfloat16(f);   // RNE
    return *reinterpret_cast<unsigned short*>(&b);
}
__device__ __forceinline__ float bf16_lo(uint32_t u) {
    uint32_t v = u << 16; return *reinterpret_cast<float*>(&v);
}
__device__ __forceinline__ float bf16_hi(uint32_t u) {
    uint32_t v = u & 0xffff0000u; return *reinterpret_cast<float*>(&v);
}

// ---------------------------------------------------------------------------
// CSR build. edge_index arrives int32 (harness converts integer inputs).
// R4: single int atomic per edge (deg computed later from CSR, no fp atomics).
// ---------------------------------------------------------------------------
__global__ void hist_kernel(const int* __restrict__ ei, int* __restrict__ cnt) {
    int e = blockIdx.x * 256 + threadIdx.x;
    if (e >= N_EDGES) return;
    atomicAdd(&cnt[ei[N_EDGES + e]], 1);
}

__global__ void scan1_kernel(const int* __restrict__ in, int* __restrict__ out,
                             int* __restrict__ bsums, int n) {
    __shared__ int tmp[256];
    int t = threadIdx.x;
    int i = blockIdx.x * 256 + t;
    int v = (i < n) ? in[i] : 0;
    tmp[t] = v;
    __syncthreads();
    for (int off = 1; off < 256; off <<= 1) {
        int u = (t >= off) ? tmp[t - off] : 0;
        __syncthreads();
        tmp[t] += u;
        __syncthreads();
    }
    if (i < n) out[i] = tmp[t] - v;          // exclusive
    if (t == 255) bsums[blockIdx.x] = tmp[255];
}

__global__ void scan2_kernel(int* __restrict__ bsums, int nb) {
    __shared__ int tmp[512];
    int t = threadIdx.x;
    int v = (t < nb) ? bsums[t] : 0;
    tmp[t] = v;
    __syncthreads();
    for (int off = 1; off < 512; off <<= 1) {
        int u = (t >= off) ? tmp[t - off] : 0;
        __syncthreads();
        tmp[t] += u;
        __syncthreads();
    }
    if (t < nb) bsums[t] = tmp[t] - v;       // exclusive
}

__global__ void scan3_kernel(int* __restrict__ row_ptr, const int* __restrict__ bsums,
                             int* __restrict__ cursor, int n, int total) {
    int i = blockIdx.x * 256 + threadIdx.x;
    if (i == 0) row_ptr[n] = total;
    if (i >= n) return;
    int v = row_ptr[i] + bsums[blockIdx.x];
    row_ptr[i] = v;
    cursor[i] = v;
}

// fill: edge -> (src, weight) pair at its target's CSR slot. One 8B store.
__global__ void fill_kernel(const int* __restrict__ ei,
                            const float* __restrict__ ew,
                            int* __restrict__ cursor,
                            int2* __restrict__ pairs) {
    int e = blockIdx.x * 256 + threadIdx.x;
    if (e >= N_EDGES) return;
    int r = ei[e];
    int c = ei[N_EDGES + e];
    float w = ew[e];
    int pos = atomicAdd(&cursor[c], 1);
    pairs[pos] = make_int2(r, __float_as_int(w));
}

// per-node: deg = sum of row weights; dis = rsqrt(deg) or 0. No atomics.
__global__ void deg_dis_kernel(const int* __restrict__ rowp,
                               const int2* __restrict__ pairs,
                               float* __restrict__ dis) {
    int v = blockIdx.x * 256 + threadIdx.x;
    if (v >= N_NODES) return;
    int b = rowp[v], e = rowp[v + 1];
    float d = 0.f;
    for (int j = b; j < e; ++j) d += __int_as_float(pairs[j].y);
    dis[v] = d > 0.f ? rsqrtf(d) : 0.f;
}

// per-node: overwrite pair weight with norm = dis[src]*w*dis[v]
__global__ void nrm_kernel(const int* __restrict__ rowp,
                           int2* __restrict__ pairs,
                           const float* __restrict__ dis) {
    int v = blockIdx.x * 256 + threadIdx.x;
    if (v >= N_NODES) return;
    float dv = dis[v];
    int b = rowp[v], e = rowp[v + 1];
    for (int j = b; j < e; ++j) {
        int2 p = pairs[j];
        pairs[j].y = __float_as_int(__int_as_float(p.y) * dis[p.x] * dv);
    }
}

// ---------------------------------------------------------------------------
// fp32 -> bf16 bulk cast (float4 -> 4x bf16 per thread)
// ---------------------------------------------------------------------------
__global__ void cast_bf16_kernel(const float* __restrict__ in,
                                 uint32_t* __restrict__ out, int n4) {
    int i = blockIdx.x * 256 + threadIdx.x;
    if (i >= n4) return;
    float4 v = ((const float4*)in)[i];
    uint32_t lo = (uint32_t)f32_to_bf16(v.x) | ((uint32_t)f32_to_bf16(v.y) << 16);
    uint32_t hi = (uint32_t)f32_to_bf16(v.z) | ((uint32_t)f32_to_bf16(v.w) << 16);
    ((uint2*)out)[i] = make_uint2(lo, hi);
}

// ---------------------------------------------------------------------------
// Weight transpose + cast: fp32 [R][C] -> bf16 [C][R]
// ---------------------------------------------------------------------------
__global__ void transpose_cast_kernel(const float* __restrict__ in,
                                      unsigned short* __restrict__ out,
                                      int R, int C) {
    int idx = blockIdx.x * 256 + threadIdx.x;
    if (idx >= R * C) return;
    int r = idx / C, c = idx % C;
    out[(size_t)c * R + r] = f32_to_bf16(in[idx]);
}

// ---------------------------------------------------------------------------
// Aggregation: one wave per node, bf16 input (uint32 = 2 dims per lane).
// out[v] = sum_e nrm[e]*feat[src[e]] (+bias). 4/2/1 edge unroll for MLP.
// ---------------------------------------------------------------------------
template <bool OUT_BF16>
__global__ void aggregate_kernel(const uint32_t* __restrict__ feat,
                                 const int* __restrict__ rowp,
                                 const int2* __restrict__ pairs,
                                 void* __restrict__ out_v,
                                 const float* __restrict__ bias) {
    int gtid = blockIdx.x * blockDim.x + threadIdx.x;
    int node = gtid >> 6;
    int lane = threadIdx.x & 63;
    if (node >= N_NODES) return;
    int beg = rowp[node];
    int end = rowp[node + 1];
    float ax = 0.f, ay = 0.f;

    int j = beg;
    for (; j + 4 <= end; j += 4) {
        int2 p0 = pairs[j], p1 = pairs[j + 1], p2 = pairs[j + 2], p3 = pairs[j + 3];
        uint32_t u0 = feat[(size_t)p0.x * 64 + lane];
        uint32_t u1 = feat[(size_t)p1.x * 64 + lane];
        uint32_t u2 = feat[(size_t)p2.x * 64 + lane];
        uint32_t u3 = feat[(size_t)p3.x * 64 + lane];
        float w0 = __int_as_float(p0.y), w1 = __int_as_float(p1.y);
        float w2 = __int_as_float(p2.y), w3 = __int_as_float(p3.y);
        ax += w0 * bf16_lo(u0) + w1 * bf16_lo(u1) + w2 * bf16_lo(u2) + w3 * bf16_lo(u3);
        ay += w0 * bf16_hi(u0) + w1 * bf16_hi(u1) + w2 * bf16_hi(u2) + w3 * bf16_hi(u3);
    }
    if (j + 2 <= end) {
        int2 p0 = pairs[j], p1 = pairs[j + 1];
        uint32_t u0 = feat[(size_t)p0.x * 64 + lane];
        uint32_t u1 = feat[(size_t)p1.x * 64 + lane];
        float w0 = __int_as_float(p0.y), w1 = __int_as_float(p1.y);
        ax += w0 * bf16_lo(u0) + w1 * bf16_lo(u1);
        ay += w0 * bf16_hi(u0) + w1 * bf16_hi(u1);
        j += 2;
    }
    if (j < end) {
        int2 p0 = pairs[j];
        uint32_t u0 = feat[(size_t)p0.x * 64 + lane];
        float w0 = __int_as_float(p0.y);
        ax += w0 * bf16_lo(u0);
        ay += w0 * bf16_hi(u0);
    }
    if (bias) {
        float2 b = *(const float2*)(bias + lane * 2);
        ax += b.x; ay += b.y;
    }
    if (OUT_BF16) {
        uint32_t p = (uint32_t)f32_to_bf16(ax) | ((uint32_t)f32_to_bf16(ay) << 16);
        ((uint32_t*)out_v)[(size_t)node * 64 + lane] = p;
    } else {
        ((float2*)out_v)[(size_t)node * 64 + lane] = make_float2(ax, ay);
    }
}

// ---------------------------------------------------------------------------
// bf16 MFMA GEMM: C[M,NC] = A[M,K] @ BT[NC,K]^T (+bias, optional relu), C bf16.
// BM=BN=128, BK=32, 256 threads (4 waves), global_load_lds width 16.
// ---------------------------------------------------------------------------
template <int K, int NC, bool RELU>
__global__ __launch_bounds__(256) void gemm_bf16(const unsigned short* __restrict__ A,
                                                 const unsigned short* __restrict__ BT,
                                                 const float* __restrict__ bias,
                                                 unsigned short* __restrict__ C,
                                                 int M) {
    constexpr int BM = 128, BN = 128, BK = 32;
    __shared__ unsigned short As[BM * BK];   // row-major [m][k], 8KB
    __shared__ unsigned short Bs[BN * BK];
    int tid = threadIdx.x;
    int wave = tid >> 6, lane = tid & 63;
    int m0 = blockIdx.x * BM, n0 = blockIdx.y * BN;
    int wr = (wave & 1) * 64, wc = (wave >> 1) * 64;
    int fr = lane & 15, fq = lane >> 4;

    f32x4 acc[4][4] = {};

    for (int k0 = 0; k0 < K; k0 += BK) {
        #pragma unroll
        for (int i = 0; i < 2; ++i) {
            int cbase = (i * 4 + wave) * 64;
            int c = cbase + lane;
            int m = c >> 2, q = c & 3;
            int gm = m0 + m; if (gm >= M) gm = M - 1;
            const unsigned short* ga = A + (size_t)gm * K + k0 + q * 8;
            __builtin_amdgcn_global_load_lds(
                (const __attribute__((address_space(1))) void*)ga,
                (__attribute__((address_space(3))) void*)(As + (size_t)cbase * 8),
                16, 0, 0);
            const unsigned short* gb = BT + (size_t)(n0 + m) * K + k0 + q * 8;
            __builtin_amdgcn_global_load_lds(
                (const __attribute__((address_space(1))) void*)gb,
                (__attribute__((address_space(3))) void*)(Bs + (size_t)cbase * 8),
                16, 0, 0);
        }
        __syncthreads();

        bf16x8 af[4], bfr[4];
        #pragma unroll
        for (int mt = 0; mt < 4; ++mt)
            af[mt] = *(const bf16x8*)(As + (wr + mt * 16 + fr) * BK + fq * 8);
        #pragma unroll
        for (int nt = 0; nt < 4; ++nt)
            bfr[nt] = *(const bf16x8*)(Bs + (wc + nt * 16 + fr) * BK + fq * 8);
        #pragma unroll
        for (int mt = 0; mt < 4; ++mt)
            #pragma unroll
            for (int nt = 0; nt < 4; ++nt)
                acc[mt][nt] = __builtin_amdgcn_mfma_f32_16x16x32_bf16(
                    af[mt], bfr[nt], acc[mt][nt], 0, 0, 0);
        __syncthreads();
    }

    // C/D layout: col=lane&15, row=(lane>>4)*4+reg (m89-verified)
    #pragma unroll
    for (int mt = 0; mt < 4; ++mt) {
        #pragma unroll
        for (int r = 0; r < 4; ++r) {
            int row = m0 + wr + mt * 16 + fq * 4 + r;
            if (row >= M) continue;
            #pragma unroll
            for (int nt = 0; nt < 4; ++nt) {
                int col = n0 + wc + nt * 16 + fr;
                float v = acc[mt][nt][r];
                if (bias) v += bias[col];
                if (RELU) v = fmaxf(v, 0.f);
                C[(size_t)row * NC + col] = f32_to_bf16(v);
            }
        }
    }
}

// ---------------------------------------------------------------------------
extern "C" void kernel_launch(void* const* d_in, const int* in_sizes, int n_in,
                              void* d_out, int out_size, void* d_ws, size_t ws_size,
                              hipStream_t stream) {
    const float* x  = (const float*)d_in[0];
    const int*   ei = (const int*)d_in[1];    // int32 (harness converts ints)
    const float* ew = (const float*)d_in[2];
    const float* W1 = (const float*)d_in[3];
    const float* b1 = (const float*)d_in[4];
    const float* W2 = (const float*)d_in[5];
    const float* b2 = (const float*)d_in[6];
    float* out = (float*)d_out;

    char* ws = (char*)d_ws;
    size_t off = 0;
    auto alloc = [&](size_t bytes) -> void* {
        void* p = ws + off;
        off = (off + bytes + 255) & ~(size_t)255;
        return p;
    };
    int*   cnt    = (int*)  alloc((size_t)N_NODES * 4);
    float* dis    = (float*)alloc((size_t)N_NODES * 4);
    int*   rowp   = (int*)  alloc((size_t)(N_NODES + 1) * 4);
    int*   cursor = (int*)  alloc((size_t)N_NODES * 4);
    int*   bsums  = (int*)  alloc(512 * 4);
    int2*  pairs  = (int2*) alloc((size_t)N_EDGES * 8);
    uint32_t* xb  = (uint32_t*)alloc((size_t)N_NODES * IN_DIM * 2);            // x bf16
    unsigned short* W1T = (unsigned short*)alloc((size_t)IN_DIM * HID_DIM * 2);
    unsigned short* W2T = (unsigned short*)alloc((size_t)HID_DIM * OUT_DIM * 2);
    unsigned short* A1  = (unsigned short*)alloc((size_t)N_NODES * IN_DIM * 2); // agg1 out / t
    unsigned short* h1  = (unsigned short*)alloc((size_t)N_NODES * HID_DIM * 2);

    hipMemsetAsync(cnt, 0, (size_t)N_NODES * 4, stream);

    int ne_blocks = (N_EDGES + 255) / 256;
    int nn_blocks = (N_NODES + 255) / 256;   // 391

    hist_kernel<<<ne_blocks, 256, 0, stream>>>(ei, cnt);
    scan1_kernel<<<nn_blocks, 256, 0, stream>>>(cnt, rowp, bsums, N_NODES);
    scan2_kernel<<<1, 512, 0, stream>>>(bsums, nn_blocks);
    scan3_kernel<<<nn_blocks, 256, 0, stream>>>(rowp, bsums, cursor, N_NODES, N_EDGES);
    fill_kernel<<<ne_blocks, 256, 0, stream>>>(ei, ew, cursor, pairs);
    deg_dis_kernel<<<nn_blocks, 256, 0, stream>>>(rowp, pairs, dis);
    nrm_kernel<<<nn_blocks, 256, 0, stream>>>(rowp, pairs, dis);

    cast_bf16_kernel<<<(N_NODES * IN_DIM / 4 + 255) / 256, 256, 0, stream>>>(
        x, xb, N_NODES * IN_DIM / 4);
    transpose_cast_kernel<<<(IN_DIM * HID_DIM + 255) / 256, 256, 0, stream>>>(W1, W1T, IN_DIM, HID_DIM);
    transpose_cast_kernel<<<(HID_DIM * OUT_DIM + 255) / 256, 256, 0, stream>>>(W2, W2T, HID_DIM, OUT_DIM);

    int agg_blocks = (N_NODES + 3) / 4;      // 4 waves/block, 1 node/wave

    // layer 1: A1 = agg(xb) [bf16], h1 = relu(A1 @ W1 + b1) [bf16]
    aggregate_kernel<true><<<agg_blocks, 256, 0, stream>>>(xb, rowp, pairs, A1, nullptr);
    dim3 g1((N_NODES + 127) / 128, HID_DIM / 128);
    gemm_bf16<IN_DIM, HID_DIM, true><<<g1, 256, 0, stream>>>(A1, W1T, b1, h1, N_NODES);

    // layer 2: t = h1 @ W2 [bf16], out = agg(t) + b2 [fp32]
    unsigned short* t = A1;
    dim3 g2((N_NODES + 127) / 128, OUT_DIM / 128);
    gemm_bf16<HID_DIM, OUT_DIM, false><<<g2, 256, 0, stream>>>(h1, W2T, nullptr, t, N_NODES);
    aggregate_kernel<false><<<agg_blocks, 256, 0, stream>>>(
        (const uint32_t*)t, rowp, pairs, out, b2);
}

// Round 5
// 316.770 us; speedup vs baseline: 1.9733x; 1.1643x over previous
//
#include <hip/hip_runtime.h>
#include <hip/hip_bf16.h>
#include <cstdint>
#include <cstddef>

#define N_NODES 100000
#define N_EDGES 800000
#define IN_DIM 128
#define HID_DIM 256
#define OUT_DIM 128

typedef __attribute__((ext_vector_type(8))) short bf16x8;
typedef __attribute__((ext_vector_type(4))) float f32x4;

__device__ __forceinline__ unsigned short f32_to_bf16(float f) {
    __hip_bfloat16 b = __float2bfloat16(f);   // RNE
    return *reinterpret_cast<unsigned short*>(&b);
}
__device__ __forceinline__ float bf16_lo(uint32_t u) {
    uint32_t v = u << 16; return *reinterpret_cast<float*>(&v);
}
__device__ __forceinline__ float bf16_hi(uint32_t u) {
    uint32_t v = u & 0xffff0000u; return *reinterpret_cast<float*>(&v);
}

// ---------------------------------------------------------------------------
// CSR build. edge_index arrives int32 (harness converts integer inputs).
// R5: rank_hist (1 atomic/edge, rank out) -> scan -> place (0 atomics).
// ---------------------------------------------------------------------------
__global__ void rank_hist_kernel(const int* __restrict__ ei,
                                 int* __restrict__ cnt,
                                 int* __restrict__ rank) {
    int e = blockIdx.x * 256 + threadIdx.x;
    if (e >= N_EDGES) return;
    rank[e] = atomicAdd(&cnt[ei[N_EDGES + e]], 1);
}

__global__ void scan1_kernel(const int* __restrict__ in, int* __restrict__ out,
                             int* __restrict__ bsums, int n) {
    __shared__ int tmp[256];
    int t = threadIdx.x;
    int i = blockIdx.x * 256 + t;
    int v = (i < n) ? in[i] : 0;
    tmp[t] = v;
    __syncthreads();
    for (int off = 1; off < 256; off <<= 1) {
        int u = (t >= off) ? tmp[t - off] : 0;
        __syncthreads();
        tmp[t] += u;
        __syncthreads();
    }
    if (i < n) out[i] = tmp[t] - v;          // exclusive
    if (t == 255) bsums[blockIdx.x] = tmp[255];
}

__global__ void scan2_kernel(int* __restrict__ bsums, int nb) {
    __shared__ int tmp[512];
    int t = threadIdx.x;
    int v = (t < nb) ? bsums[t] : 0;
    tmp[t] = v;
    __syncthreads();
    for (int off = 1; off < 512; off <<= 1) {
        int u = (t >= off) ? tmp[t - off] : 0;
        __syncthreads();
        tmp[t] += u;
        __syncthreads();
    }
    if (t < nb) bsums[t] = tmp[t] - v;       // exclusive
}

__global__ void scan3_kernel(int* __restrict__ rowp, const int* __restrict__ bsums,
                             int n, int total) {
    int i = blockIdx.x * 256 + threadIdx.x;
    if (i == 0) rowp[n] = total;
    if (i >= n) return;
    rowp[i] += bsums[blockIdx.x];
}

// place: no atomics — slot = rowp[col] + rank[e]. One scattered 8B store.
__global__ void place_kernel(const int* __restrict__ ei,
                             const float* __restrict__ ew,
                             const int* __restrict__ rank,
                             const int* __restrict__ rowp,
                             int2* __restrict__ pairs) {
    int e = blockIdx.x * 256 + threadIdx.x;
    if (e >= N_EDGES) return;
    int c = ei[N_EDGES + e];
    int pos = rowp[c] + rank[e];
    pairs[pos] = make_int2(ei[e], __float_as_int(ew[e]));
}

// per-node: deg = sum of row weights; dis = rsqrt(deg) or 0. No atomics.
__global__ void deg_dis_kernel(const int* __restrict__ rowp,
                               const int2* __restrict__ pairs,
                               float* __restrict__ dis) {
    int v = blockIdx.x * 256 + threadIdx.x;
    if (v >= N_NODES) return;
    int b = rowp[v], e = rowp[v + 1];
    float d = 0.f;
    for (int j = b; j < e; ++j) d += __int_as_float(pairs[j].y);
    dis[v] = d > 0.f ? rsqrtf(d) : 0.f;
}

// ---------------------------------------------------------------------------
// Fused prep: xb = bf16(x); W1T = bf16(W1^T); W2T = bf16(W2^T). One launch.
// Block ranges: [0,12500) xb, [12500,12628) W1T, [12628,12756) W2T.
// ---------------------------------------------------------------------------
__global__ void prep_kernel(const float* __restrict__ x, uint32_t* __restrict__ xb,
                            const float* __restrict__ W1, unsigned short* __restrict__ W1T,
                            const float* __restrict__ W2, unsigned short* __restrict__ W2T) {
    int b = blockIdx.x;
    if (b < 12500) {                                   // 12500*256*4 = 100000*128
        int i = b * 256 + threadIdx.x;
        float4 v = ((const float4*)x)[i];
        uint32_t lo = (uint32_t)f32_to_bf16(v.x) | ((uint32_t)f32_to_bf16(v.y) << 16);
        uint32_t hi = (uint32_t)f32_to_bf16(v.z) | ((uint32_t)f32_to_bf16(v.w) << 16);
        ((uint2*)xb)[i] = make_uint2(lo, hi);
    } else if (b < 12628) {                            // 128*256 = IN_DIM*HID_DIM
        int idx = (b - 12500) * 256 + threadIdx.x;
        int r = idx >> 8, c = idx & 255;               // W1 [128][256]
        W1T[c * IN_DIM + r] = f32_to_bf16(W1[idx]);
    } else {                                           // HID_DIM*OUT_DIM
        int idx = (b - 12628) * 256 + threadIdx.x;
        int r = idx >> 7, c = idx & 127;               // W2 [256][128]
        W2T[c * HID_DIM + r] = f32_to_bf16(W2[idx]);
    }
}

// ---------------------------------------------------------------------------
// Aggregation: 2 nodes per wave (32 lanes/node, uint2 = 4 bf16 dims per lane).
// out[v] = sum_e (w*dis[src]*dis[v]) * feat[src]  (+bias). Unroll 4/2/1.
// ---------------------------------------------------------------------------
template <bool OUT_BF16>
__global__ void aggregate_kernel(const uint2* __restrict__ feat,
                                 const int* __restrict__ rowp,
                                 const int2* __restrict__ pairs,
                                 const float* __restrict__ dis,
                                 void* __restrict__ out_v,
                                 const float* __restrict__ bias) {
    int gtid = blockIdx.x * blockDim.x + threadIdx.x;
    int node = gtid >> 5;
    int lane = threadIdx.x & 31;
    if (node >= N_NODES) return;
    int beg = rowp[node], end = rowp[node + 1];
    float dv = dis[node];
    float ax = 0.f, ay = 0.f, az = 0.f, aw = 0.f;

    int j = beg;
    for (; j + 4 <= end; j += 4) {
        int2 p[4]; uint2 u[4]; float d[4];
        #pragma unroll
        for (int q = 0; q < 4; ++q) p[q] = pairs[j + q];
        #pragma unroll
        for (int q = 0; q < 4; ++q) {
            u[q] = feat[(size_t)p[q].x * 32 + lane];
            d[q] = dis[p[q].x];
        }
        #pragma unroll
        for (int q = 0; q < 4; ++q) {
            float w = __int_as_float(p[q].y) * d[q] * dv;
            ax += w * bf16_lo(u[q].x); ay += w * bf16_hi(u[q].x);
            az += w * bf16_lo(u[q].y); aw += w * bf16_hi(u[q].y);
        }
    }
    if (j + 2 <= end) {
        int2 p0 = pairs[j], p1 = pairs[j + 1];
        uint2 u0 = feat[(size_t)p0.x * 32 + lane];
        uint2 u1 = feat[(size_t)p1.x * 32 + lane];
        float w0 = __int_as_float(p0.y) * dis[p0.x] * dv;
        float w1 = __int_as_float(p1.y) * dis[p1.x] * dv;
        ax += w0 * bf16_lo(u0.x) + w1 * bf16_lo(u1.x);
        ay += w0 * bf16_hi(u0.x) + w1 * bf16_hi(u1.x);
        az += w0 * bf16_lo(u0.y) + w1 * bf16_lo(u1.y);
        aw += w0 * bf16_hi(u0.y) + w1 * bf16_hi(u1.y);
        j += 2;
    }
    if (j < end) {
        int2 p0 = pairs[j];
        uint2 u0 = feat[(size_t)p0.x * 32 + lane];
        float w0 = __int_as_float(p0.y) * dis[p0.x] * dv;
        ax += w0 * bf16_lo(u0.x); ay += w0 * bf16_hi(u0.x);
        az += w0 * bf16_lo(u0.y); aw += w0 * bf16_hi(u0.y);
    }
    if (bias) {
        float4 b = ((const float4*)bias)[lane];
        ax += b.x; ay += b.y; az += b.z; aw += b.w;
    }
    if (OUT_BF16) {
        uint2 o;
        o.x = (uint32_t)f32_to_bf16(ax) | ((uint32_t)f32_to_bf16(ay) << 16);
        o.y = (uint32_t)f32_to_bf16(az) | ((uint32_t)f32_to_bf16(aw) << 16);
        ((uint2*)out_v)[(size_t)node * 32 + lane] = o;
    } else {
        ((float4*)out_v)[(size_t)node * 32 + lane] = make_float4(ax, ay, az, aw);
    }
}

// ---------------------------------------------------------------------------
// bf16 MFMA GEMM: C[M,NC] = A[M,K] @ BT[NC,K]^T (+bias, optional relu), C bf16.
// BM=BN=128, BK=64, 256 threads (4 waves). XOR-swizzled LDS chunks: LDS chunk
// i holds global 16B-chunk (m=i>>3, q=(i&7)^(m&7)) so ds_read_b128 at 128B row
// stride lands 2-way (free) instead of 16-way conflicted, while the
// global_load_lds dest stays wave-uniform-base + lane*16 (m104/m108 rule).
// ---------------------------------------------------------------------------
template <int K, int NC, bool RELU>
__global__ __launch_bounds__(256) void gemm_bf16(const unsigned short* __restrict__ A,
                                                 const unsigned short* __restrict__ BT,
                                                 const float* __restrict__ bias,
                                                 unsigned short* __restrict__ C,
                                                 int M) {
    constexpr int BM = 128, BN = 128, BK = 64;
    __shared__ unsigned short As[BM * BK];   // 16KB, chunk-addressed
    __shared__ unsigned short Bs[BN * BK];
    int tid = threadIdx.x;
    int wave = tid >> 6, lane = tid & 63;
    int m0 = blockIdx.x * BM, n0 = blockIdx.y * BN;
    int wr = (wave & 1) * 64, wc = (wave >> 1) * 64;
    int fr = lane & 15, fq = lane >> 4;

    f32x4 acc[4][4] = {};

    for (int k0 = 0; k0 < K; k0 += BK) {
        // 1024 chunks/tile, 4 issues per wave per tile.
        #pragma unroll
        for (int i = 0; i < 4; ++i) {
            int cbase = (i * 4 + wave) * 64;
            int c = cbase + lane;
            int m = c >> 3, qg = (c & 7) ^ (m & 7);    // swizzled source chunk
            int gm = m0 + m; if (gm >= M) gm = M - 1;
            const unsigned short* ga = A + (size_t)gm * K + k0 + qg * 8;
            __builtin_amdgcn_global_load_lds(
                (const __attribute__((address_space(1))) void*)ga,
                (__attribute__((address_space(3))) void*)(As + (size_t)cbase * 8),
                16, 0, 0);
            const unsigned short* gb = BT + (size_t)(n0 + m) * K + k0 + qg * 8;
            __builtin_amdgcn_global_load_lds(
                (const __attribute__((address_space(1))) void*)gb,
                (__attribute__((address_space(3))) void*)(Bs + (size_t)cbase * 8),
                16, 0, 0);
        }
        __syncthreads();

        #pragma unroll
        for (int kf = 0; kf < 2; ++kf) {
            int swz = ((kf * 4 + fq) ^ (fr & 7)) * 8;  // same for all mt/nt tiles
            bf16x8 af[4], bfr[4];
            #pragma unroll
            for (int mt = 0; mt < 4; ++mt)
                af[mt] = *(const bf16x8*)(As + (wr + mt * 16 + fr) * BK + swz);
            #pragma unroll
            for (int nt = 0; nt < 4; ++nt)
                bfr[nt] = *(const bf16x8*)(Bs + (wc + nt * 16 + fr) * BK + swz);
            #pragma unroll
            for (int mt = 0; mt < 4; ++mt)
                #pragma unroll
                for (int nt = 0; nt < 4; ++nt)
                    acc[mt][nt] = __builtin_amdgcn_mfma_f32_16x16x32_bf16(
                        af[mt], bfr[nt], acc[mt][nt], 0, 0, 0);
        }
        __syncthreads();
    }

    // C/D layout: col=lane&15, row=(lane>>4)*4+reg (m89-verified)
    #pragma unroll
    for (int mt = 0; mt < 4; ++mt) {
        #pragma unroll
        for (int r = 0; r < 4; ++r) {
            int row = m0 + wr + mt * 16 + fq * 4 + r;
            if (row >= M) continue;
            #pragma unroll
            for (int nt = 0; nt < 4; ++nt) {
                int col = n0 + wc + nt * 16 + fr;
                float v = acc[mt][nt][r];
                if (bias) v += bias[col];
                if (RELU) v = fmaxf(v, 0.f);
                C[(size_t)row * NC + col] = f32_to_bf16(v);
            }
        }
    }
}

// ---------------------------------------------------------------------------
extern "C" void kernel_launch(void* const* d_in, const int* in_sizes, int n_in,
                              void* d_out, int out_size, void* d_ws, size_t ws_size,
                              hipStream_t stream) {
    const float* x  = (const float*)d_in[0];
    const int*   ei = (const int*)d_in[1];    // int32 (harness converts ints)
    const float* ew = (const float*)d_in[2];
    const float* W1 = (const float*)d_in[3];
    const float* b1 = (const float*)d_in[4];
    const float* W2 = (const float*)d_in[5];
    const float* b2 = (const float*)d_in[6];
    float* out = (float*)d_out;

    char* ws = (char*)d_ws;
    size_t off = 0;
    auto alloc = [&](size_t bytes) -> void* {
        void* p = ws + off;
        off = (off + bytes + 255) & ~(size_t)255;
        return p;
    };
    int*   cnt   = (int*)  alloc((size_t)N_NODES * 4);
    float* dis   = (float*)alloc((size_t)N_NODES * 4);
    int*   rowp  = (int*)  alloc((size_t)(N_NODES + 1) * 4);
    int*   bsums = (int*)  alloc(512 * 4);
    int*   rank  = (int*)  alloc((size_t)N_EDGES * 4);
    int2*  pairs = (int2*) alloc((size_t)N_EDGES * 8);
    uint32_t* xb = (uint32_t*)alloc((size_t)N_NODES * IN_DIM * 2);
    unsigned short* W1T = (unsigned short*)alloc((size_t)IN_DIM * HID_DIM * 2);
    unsigned short* W2T = (unsigned short*)alloc((size_t)HID_DIM * OUT_DIM * 2);
    unsigned short* A1  = (unsigned short*)alloc((size_t)N_NODES * IN_DIM * 2); // agg1 out / t
    unsigned short* h1  = (unsigned short*)alloc((size_t)N_NODES * HID_DIM * 2);

    hipMemsetAsync(cnt, 0, (size_t)N_NODES * 4, stream);

    int ne_blocks = (N_EDGES + 255) / 256;
    int nn_blocks = (N_NODES + 255) / 256;   // 391

    rank_hist_kernel<<<ne_blocks, 256, 0, stream>>>(ei, cnt, rank);
    scan1_kernel<<<nn_blocks, 256, 0, stream>>>(cnt, rowp, bsums, N_NODES);
    scan2_kernel<<<1, 512, 0, stream>>>(bsums, nn_blocks);
    scan3_kernel<<<nn_blocks, 256, 0, stream>>>(rowp, bsums, N_NODES, N_EDGES);
    place_kernel<<<ne_blocks, 256, 0, stream>>>(ei, ew, rank, rowp, pairs);
    deg_dis_kernel<<<nn_blocks, 256, 0, stream>>>(rowp, pairs, dis);
    prep_kernel<<<12756, 256, 0, stream>>>(x, xb, W1, W1T, W2, W2T);

    int agg_blocks = (N_NODES * 32) / 256;   // 12500, exact

    // layer 1: A1 = agg(xb) [bf16], h1 = relu(A1 @ W1 + b1) [bf16]
    aggregate_kernel<true><<<agg_blocks, 256, 0, stream>>>(
        (const uint2*)xb, rowp, pairs, dis, A1, nullptr);
    dim3 g1((N_NODES + 127) / 128, HID_DIM / 128);
    gemm_bf16<IN_DIM, HID_DIM, true><<<g1, 256, 0, stream>>>(A1, W1T, b1, h1, N_NODES);

    // layer 2: t = h1 @ W2 [bf16], out = agg(t) + b2 [fp32]
    unsigned short* t = A1;
    dim3 g2((N_NODES + 127) / 128, OUT_DIM / 128);
    gemm_bf16<HID_DIM, OUT_DIM, false><<<g2, 256, 0, stream>>>(h1, W2T, nullptr, t, N_NODES);
    aggregate_kernel<false><<<agg_blocks, 256, 0, stream>>>(
        (const uint2*)t, rowp, pairs, dis, out, b2);
}

// Round 6
// 297.864 us; speedup vs baseline: 2.0986x; 1.0635x over previous
//
#include <hip/hip_runtime.h>
#include <hip/hip_bf16.h>
#include <cstdint>
#include <cstddef>

#define N_NODES 100000
#define N_EDGES 800000
#define IN_DIM 128
#define HID_DIM 256
#define OUT_DIM 128

typedef __attribute__((ext_vector_type(8))) short bf16x8;
typedef __attribute__((ext_vector_type(4))) float f32x4;

__device__ __forceinline__ unsigned short f32_to_bf16(float f) {
    __hip_bfloat16 b = __float2bfloat16(f);   // RNE
    return *reinterpret_cast<unsigned short*>(&b);
}
__device__ __forceinline__ float bf16_lo(uint32_t u) {
    uint32_t v = u << 16; return *reinterpret_cast<float*>(&v);
}
__device__ __forceinline__ float bf16_hi(uint32_t u) {
    uint32_t v = u & 0xffff0000u; return *reinterpret_cast<float*>(&v);
}

// ---------------------------------------------------------------------------
// CSR build. edge_index arrives int32 (harness converts integer inputs).
// rank_hist (1 atomic/edge, rank out) -> scan -> place (0 atomics).
// ---------------------------------------------------------------------------
__global__ void rank_hist_kernel(const int* __restrict__ ei,
                                 int* __restrict__ cnt,
                                 int* __restrict__ rank) {
    int e = blockIdx.x * 256 + threadIdx.x;
    if (e >= N_EDGES) return;
    rank[e] = atomicAdd(&cnt[ei[N_EDGES + e]], 1);
}

__global__ void scan1_kernel(const int* __restrict__ in, int* __restrict__ out,
                             int* __restrict__ bsums, int n) {
    __shared__ int tmp[256];
    int t = threadIdx.x;
    int i = blockIdx.x * 256 + t;
    int v = (i < n) ? in[i] : 0;
    tmp[t] = v;
    __syncthreads();
    for (int off = 1; off < 256; off <<= 1) {
        int u = (t >= off) ? tmp[t - off] : 0;
        __syncthreads();
        tmp[t] += u;
        __syncthreads();
    }
    if (i < n) out[i] = tmp[t] - v;          // exclusive
    if (t == 255) bsums[blockIdx.x] = tmp[255];
}

__global__ void scan2_kernel(int* __restrict__ bsums, int nb) {
    __shared__ int tmp[512];
    int t = threadIdx.x;
    int v = (t < nb) ? bsums[t] : 0;
    tmp[t] = v;
    __syncthreads();
    for (int off = 1; off < 512; off <<= 1) {
        int u = (t >= off) ? tmp[t - off] : 0;
        __syncthreads();
        tmp[t] += u;
        __syncthreads();
    }
    if (t < nb) bsums[t] = tmp[t] - v;       // exclusive
}

__global__ void scan3_kernel(int* __restrict__ rowp, const int* __restrict__ bsums,
                             int n, int total) {
    int i = blockIdx.x * 256 + threadIdx.x;
    if (i == 0) rowp[n] = total;
    if (i >= n) return;
    rowp[i] += bsums[blockIdx.x];
}

// place: no atomics — slot = rowp[col] + rank[e]. One scattered 8B store.
__global__ void place_kernel(const int* __restrict__ ei,
                             const float* __restrict__ ew,
                             const int* __restrict__ rank,
                             const int* __restrict__ rowp,
                             int2* __restrict__ pairs) {
    int e = blockIdx.x * 256 + threadIdx.x;
    if (e >= N_EDGES) return;
    int c = ei[N_EDGES + e];
    int pos = rowp[c] + rank[e];
    pairs[pos] = make_int2(ei[e], __float_as_int(ew[e]));
}

// per-node: deg = sum of row weights; dis = rsqrt(deg) or 0. No atomics.
__global__ void deg_dis_kernel(const int* __restrict__ rowp,
                               const int2* __restrict__ pairs,
                               float* __restrict__ dis) {
    int v = blockIdx.x * 256 + threadIdx.x;
    if (v >= N_NODES) return;
    int b = rowp[v], e = rowp[v + 1];
    float d = 0.f;
    for (int j = b; j < e; ++j) d += __int_as_float(pairs[j].y);
    dis[v] = d > 0.f ? rsqrtf(d) : 0.f;
}

// ---------------------------------------------------------------------------
// Fused prep: xb = bf16(x); W1T = bf16(W1^T); W2T = bf16(W2^T). One launch.
// ---------------------------------------------------------------------------
__global__ void prep_kernel(const float* __restrict__ x, uint32_t* __restrict__ xb,
                            const float* __restrict__ W1, unsigned short* __restrict__ W1T,
                            const float* __restrict__ W2, unsigned short* __restrict__ W2T) {
    int b = blockIdx.x;
    if (b < 12500) {                                   // 12500*256*4 = 100000*128
        int i = b * 256 + threadIdx.x;
        float4 v = ((const float4*)x)[i];
        uint32_t lo = (uint32_t)f32_to_bf16(v.x) | ((uint32_t)f32_to_bf16(v.y) << 16);
        uint32_t hi = (uint32_t)f32_to_bf16(v.z) | ((uint32_t)f32_to_bf16(v.w) << 16);
        ((uint2*)xb)[i] = make_uint2(lo, hi);
    } else if (b < 12628) {                            // 128*256 = IN_DIM*HID_DIM
        int idx = (b - 12500) * 256 + threadIdx.x;
        int r = idx >> 8, c = idx & 255;               // W1 [128][256]
        W1T[c * IN_DIM + r] = f32_to_bf16(W1[idx]);
    } else {                                           // HID_DIM*OUT_DIM
        int idx = (b - 12628) * 256 + threadIdx.x;
        int r = idx >> 7, c = idx & 127;               // W2 [256][128]
        W2T[c * HID_DIM + r] = f32_to_bf16(W2[idx]);
    }
}

// ---------------------------------------------------------------------------
// Aggregation: 2 nodes per wave (32 lanes/node, uint2 = 4 bf16 dims per lane).
// out[v] = sum_e (w*dis[src]*dis[v]) * feat[src]  (+bias). Unroll 4/2/1.
// ---------------------------------------------------------------------------
template <bool OUT_BF16>
__global__ void aggregate_kernel(const uint2* __restrict__ feat,
                                 const int* __restrict__ rowp,
                                 const int2* __restrict__ pairs,
                                 const float* __restrict__ dis,
                                 void* __restrict__ out_v,
                                 const float* __restrict__ bias) {
    int gtid = blockIdx.x * blockDim.x + threadIdx.x;
    int node = gtid >> 5;
    int lane = threadIdx.x & 31;
    if (node >= N_NODES) return;
    int beg = rowp[node], end = rowp[node + 1];
    float dv = dis[node];
    float ax = 0.f, ay = 0.f, az = 0.f, aw = 0.f;

    int j = beg;
    for (; j + 4 <= end; j += 4) {
        int2 p[4]; uint2 u[4]; float d[4];
        #pragma unroll
        for (int q = 0; q < 4; ++q) p[q] = pairs[j + q];
        #pragma unroll
        for (int q = 0; q < 4; ++q) {
            u[q] = feat[(size_t)p[q].x * 32 + lane];
            d[q] = dis[p[q].x];
        }
        #pragma unroll
        for (int q = 0; q < 4; ++q) {
            float w = __int_as_float(p[q].y) * d[q] * dv;
            ax += w * bf16_lo(u[q].x); ay += w * bf16_hi(u[q].x);
            az += w * bf16_lo(u[q].y); aw += w * bf16_hi(u[q].y);
        }
    }
    if (j + 2 <= end) {
        int2 p0 = pairs[j], p1 = pairs[j + 1];
        uint2 u0 = feat[(size_t)p0.x * 32 + lane];
        uint2 u1 = feat[(size_t)p1.x * 32 + lane];
        float w0 = __int_as_float(p0.y) * dis[p0.x] * dv;
        float w1 = __int_as_float(p1.y) * dis[p1.x] * dv;
        ax += w0 * bf16_lo(u0.x) + w1 * bf16_lo(u1.x);
        ay += w0 * bf16_hi(u0.x) + w1 * bf16_hi(u1.x);
        az += w0 * bf16_lo(u0.y) + w1 * bf16_lo(u1.y);
        aw += w0 * bf16_hi(u0.y) + w1 * bf16_hi(u1.y);
        j += 2;
    }
    if (j < end) {
        int2 p0 = pairs[j];
        uint2 u0 = feat[(size_t)p0.x * 32 + lane];
        float w0 = __int_as_float(p0.y) * dis[p0.x] * dv;
        ax += w0 * bf16_lo(u0.x); ay += w0 * bf16_hi(u0.x);
        az += w0 * bf16_lo(u0.y); aw += w0 * bf16_hi(u0.y);
    }
    if (bias) {
        float4 b = ((const float4*)bias)[lane];
        ax += b.x; ay += b.y; az += b.z; aw += b.w;
    }
    if (OUT_BF16) {
        uint2 o;
        o.x = (uint32_t)f32_to_bf16(ax) | ((uint32_t)f32_to_bf16(ay) << 16);
        o.y = (uint32_t)f32_to_bf16(az) | ((uint32_t)f32_to_bf16(aw) << 16);
        ((uint2*)out_v)[(size_t)node * 32 + lane] = o;
    } else {
        ((float4*)out_v)[(size_t)node * 32 + lane] = make_float4(ax, ay, az, aw);
    }
}

// ---------------------------------------------------------------------------
// Fused 2-layer GEMM: T = relu(A @ W1 + b1) @ W2, all bf16 in/out, fp32 acc.
// Block = 128 rows, 4 waves in 2x2 (64x64 each). h never touches HBM:
//  - stage A tile (128x128 bf16, 32KB) via global_load_lds, XOR-swizzled chunks
//    (measured 0 bank conflicts with this pattern in R5);
//  - per 128-col half of h: MFMA A@W1 (W1T B-frags streamed from L2-resident
//    global), +b1, relu, bf16 -> Hs LDS ([128][136] padded rows, VALU-written
//    so padding is legal; 272B stride => conflict-free-ish reads);
//  - accumulate acc_t += Hs @ W2 (W2T frags from L2).
// Traffic: read A (25.6MB) + write T (25.6MB); h1's 102MB round-trip is gone.
// ---------------------------------------------------------------------------
__global__ __launch_bounds__(256) void gemm_fused_kernel(
    const unsigned short* __restrict__ A,     // [M][128] bf16
    const unsigned short* __restrict__ W1T,   // [256][128] bf16
    const float* __restrict__ b1,             // [256]
    const unsigned short* __restrict__ W2T,   // [128][256] bf16
    unsigned short* __restrict__ T,           // [M][128] bf16
    int M) {
    __shared__ unsigned short As[128 * 128];  // 32KB, chunk-swizzled
    __shared__ unsigned short Hs[128 * 136];  // 34KB, padded rows
    int tid = threadIdx.x;
    int wave = tid >> 6, lane = tid & 63;
    int m0 = blockIdx.x * 128;
    int wr = (wave & 1) * 64, wc = (wave >> 1) * 64;
    int fr = lane & 15, fq = lane >> 4;

    // stage A block: 2048 16B-chunks, 8 rounds of 256 lanes
    #pragma unroll
    for (int i = 0; i < 8; ++i) {
        int cbase = (i * 4 + wave) * 64;
        int c = cbase + lane;
        int m = c >> 4, cl = c & 15;
        int qg = ((cl & 7) ^ (m & 7)) | (cl & 8);   // swizzled source chunk
        int gm = m0 + m; if (gm >= M) gm = M - 1;
        const unsigned short* ga = A + (size_t)gm * 128 + qg * 8;
        __builtin_amdgcn_global_load_lds(
            (const __attribute__((address_space(1))) void*)ga,
            (__attribute__((address_space(3))) void*)(As + (size_t)cbase * 8),
            16, 0, 0);
    }
    __syncthreads();

    f32x4 acc_t[4][4] = {};
    #pragma unroll
    for (int nh = 0; nh < 2; ++nh) {
        // phase A: acc_h = A_tile @ W1T[nh half]
        f32x4 acc_h[4][4] = {};
        #pragma unroll
        for (int ks = 0; ks < 4; ++ks) {
            int q = ks * 4 + fq;
            int cl = ((q & 7) ^ (fr & 7)) | (q & 8);
            bf16x8 af[4], wf[4];
            #pragma unroll
            for (int mt = 0; mt < 4; ++mt)
                af[mt] = *(const bf16x8*)(As + (wr + mt * 16 + fr) * 128 + cl * 8);
            #pragma unroll
            for (int nt = 0; nt < 4; ++nt)
                wf[nt] = *(const bf16x8*)(W1T +
                    (size_t)(nh * 128 + wc + nt * 16 + fr) * 128 + ks * 32 + fq * 8);
            #pragma unroll
            for (int mt = 0; mt < 4; ++mt)
                #pragma unroll
                for (int nt = 0; nt < 4; ++nt)
                    acc_h[mt][nt] = __builtin_amdgcn_mfma_f32_16x16x32_bf16(
                        af[mt], wf[nt], acc_h[mt][nt], 0, 0, 0);
        }
        float bv[4];
        #pragma unroll
        for (int nt = 0; nt < 4; ++nt) bv[nt] = b1[nh * 128 + wc + nt * 16 + fr];
        __syncthreads();   // prior half's Hs consumers done
        #pragma unroll
        for (int mt = 0; mt < 4; ++mt)
            #pragma unroll
            for (int r = 0; r < 4; ++r) {
                int row = wr + mt * 16 + fq * 4 + r;
                #pragma unroll
                for (int nt = 0; nt < 4; ++nt) {
                    float v = fmaxf(acc_h[mt][nt][r] + bv[nt], 0.f);
                    Hs[row * 136 + wc + nt * 16 + fr] = f32_to_bf16(v);
                }
            }
        __syncthreads();   // Hs ready
        // phase B: acc_t += Hs @ W2T[:, nh half]
        #pragma unroll
        for (int ks = 0; ks < 4; ++ks) {
            bf16x8 hf[4], wf[4];
            #pragma unroll
            for (int mt = 0; mt < 4; ++mt)
                hf[mt] = *(const bf16x8*)(Hs + (wr + mt * 16 + fr) * 136 + ks * 32 + fq * 8);
            #pragma unroll
            for (int nt = 0; nt < 4; ++nt)
                wf[nt] = *(const bf16x8*)(W2T +
                    (size_t)(wc + nt * 16 + fr) * 256 + nh * 128 + ks * 32 + fq * 8);
            #pragma unroll
            for (int mt = 0; mt < 4; ++mt)
                #pragma unroll
                for (int nt = 0; nt < 4; ++nt)
                    acc_t[mt][nt] = __builtin_amdgcn_mfma_f32_16x16x32_bf16(
                        hf[mt], wf[nt], acc_t[mt][nt], 0, 0, 0);
        }
    }

    // epilogue: C/D layout col=lane&15, row=(lane>>4)*4+reg (m89-verified)
    #pragma unroll
    for (int mt = 0; mt < 4; ++mt)
        #pragma unroll
        for (int r = 0; r < 4; ++r) {
            int row = m0 + wr + mt * 16 + fq * 4 + r;
            if (row >= M) continue;
            #pragma unroll
            for (int nt = 0; nt < 4; ++nt)
                T[(size_t)row * 128 + wc + nt * 16 + fr] = f32_to_bf16(acc_t[mt][nt][r]);
        }
}

// ---------------------------------------------------------------------------
extern "C" void kernel_launch(void* const* d_in, const int* in_sizes, int n_in,
                              void* d_out, int out_size, void* d_ws, size_t ws_size,
                              hipStream_t stream) {
    const float* x  = (const float*)d_in[0];
    const int*   ei = (const int*)d_in[1];    // int32 (harness converts ints)
    const float* ew = (const float*)d_in[2];
    const float* W1 = (const float*)d_in[3];
    const float* b1 = (const float*)d_in[4];
    const float* W2 = (const float*)d_in[5];
    const float* b2 = (const float*)d_in[6];
    float* out = (float*)d_out;

    char* ws = (char*)d_ws;
    size_t off = 0;
    auto alloc = [&](size_t bytes) -> void* {
        void* p = ws + off;
        off = (off + bytes + 255) & ~(size_t)255;
        return p;
    };
    int*   cnt   = (int*)  alloc((size_t)N_NODES * 4);
    float* dis   = (float*)alloc((size_t)N_NODES * 4);
    int*   rowp  = (int*)  alloc((size_t)(N_NODES + 1) * 4);
    int*   bsums = (int*)  alloc(512 * 4);
    int*   rank  = (int*)  alloc((size_t)N_EDGES * 4);
    int2*  pairs = (int2*) alloc((size_t)N_EDGES * 8);
    uint32_t* xb = (uint32_t*)alloc((size_t)N_NODES * IN_DIM * 2);
    unsigned short* W1T = (unsigned short*)alloc((size_t)IN_DIM * HID_DIM * 2);
    unsigned short* W2T = (unsigned short*)alloc((size_t)HID_DIM * OUT_DIM * 2);
    unsigned short* A1  = (unsigned short*)alloc((size_t)N_NODES * IN_DIM * 2);
    unsigned short* t   = (unsigned short*)alloc((size_t)N_NODES * OUT_DIM * 2);

    hipMemsetAsync(cnt, 0, (size_t)N_NODES * 4, stream);

    int ne_blocks = (N_EDGES + 255) / 256;
    int nn_blocks = (N_NODES + 255) / 256;   // 391

    rank_hist_kernel<<<ne_blocks, 256, 0, stream>>>(ei, cnt, rank);
    scan1_kernel<<<nn_blocks, 256, 0, stream>>>(cnt, rowp, bsums, N_NODES);
    scan2_kernel<<<1, 512, 0, stream>>>(bsums, nn_blocks);
    scan3_kernel<<<nn_blocks, 256, 0, stream>>>(rowp, bsums, N_NODES, N_EDGES);
    place_kernel<<<ne_blocks, 256, 0, stream>>>(ei, ew, rank, rowp, pairs);
    deg_dis_kernel<<<nn_blocks, 256, 0, stream>>>(rowp, pairs, dis);
    prep_kernel<<<12756, 256, 0, stream>>>(x, xb, W1, W1T, W2, W2T);

    int agg_blocks = (N_NODES * 32) / 256;   // 12500, exact

    // layer 1 aggregate: A1 = agg(xb) [bf16]
    aggregate_kernel<true><<<agg_blocks, 256, 0, stream>>>(
        (const uint2*)xb, rowp, pairs, dis, A1, nullptr);

    // fused dense stack: t = relu(A1 @ W1 + b1) @ W2  [bf16]
    gemm_fused_kernel<<<(N_NODES + 127) / 128, 256, 0, stream>>>(
        A1, W1T, b1, W2T, t, N_NODES);

    // layer 2 aggregate: out = agg(t) + b2 [fp32]
    aggregate_kernel<false><<<agg_blocks, 256, 0, stream>>>(
        (const uint2*)t, rowp, pairs, dis, out, b2);
}

// Round 7
// 279.261 us; speedup vs baseline: 2.2384x; 1.0666x over previous
//
#include <hip/hip_runtime.h>
#include <hip/hip_bf16.h>
#include <cstdint>
#include <cstddef>

#define N_NODES 100000
#define N_EDGES 800000
#define IN_DIM 128
#define HID_DIM 256
#define OUT_DIM 128

typedef __attribute__((ext_vector_type(8))) short bf16x8;
typedef __attribute__((ext_vector_type(4))) float f32x4;

__device__ __forceinline__ unsigned short f32_to_bf16(float f) {
    __hip_bfloat16 b = __float2bfloat16(f);   // RNE
    return *reinterpret_cast<unsigned short*>(&b);
}
__device__ __forceinline__ float bf16_lo(uint32_t u) {
    uint32_t v = u << 16; return *reinterpret_cast<float*>(&v);
}
__device__ __forceinline__ float bf16_hi(uint32_t u) {
    uint32_t v = u & 0xffff0000u; return *reinterpret_cast<float*>(&v);
}

// ---------------------------------------------------------------------------
// CSR build. edge_index arrives int32 (harness converts integer inputs).
// rank_hist (1 atomic/edge, rank out) -> scan -> place (0 atomics).
// ---------------------------------------------------------------------------
__global__ void rank_hist_kernel(const int* __restrict__ ei,
                                 int* __restrict__ cnt,
                                 int* __restrict__ rank) {
    int e = blockIdx.x * 256 + threadIdx.x;
    if (e >= N_EDGES) return;
    rank[e] = atomicAdd(&cnt[ei[N_EDGES + e]], 1);
}

__global__ void scan1_kernel(const int* __restrict__ in, int* __restrict__ out,
                             int* __restrict__ bsums, int n) {
    __shared__ int tmp[256];
    int t = threadIdx.x;
    int i = blockIdx.x * 256 + t;
    int v = (i < n) ? in[i] : 0;
    tmp[t] = v;
    __syncthreads();
    for (int off = 1; off < 256; off <<= 1) {
        int u = (t >= off) ? tmp[t - off] : 0;
        __syncthreads();
        tmp[t] += u;
        __syncthreads();
    }
    if (i < n) out[i] = tmp[t] - v;          // exclusive
    if (t == 255) bsums[blockIdx.x] = tmp[255];
}

__global__ void scan2_kernel(int* __restrict__ bsums, int nb) {
    __shared__ int tmp[512];
    int t = threadIdx.x;
    int v = (t < nb) ? bsums[t] : 0;
    tmp[t] = v;
    __syncthreads();
    for (int off = 1; off < 512; off <<= 1) {
        int u = (t >= off) ? tmp[t - off] : 0;
        __syncthreads();
        tmp[t] += u;
        __syncthreads();
    }
    if (t < nb) bsums[t] = tmp[t] - v;       // exclusive
}

__global__ void scan3_kernel(int* __restrict__ rowp, const int* __restrict__ bsums,
                             int n, int total) {
    int i = blockIdx.x * 256 + threadIdx.x;
    if (i == 0) rowp[n] = total;
    if (i >= n) return;
    rowp[i] += bsums[blockIdx.x];
}

// place: no atomics — slot = rowp[col] + rank[e]. One scattered 8B store.
__global__ void place_kernel(const int* __restrict__ ei,
                             const float* __restrict__ ew,
                             const int* __restrict__ rank,
                             const int* __restrict__ rowp,
                             int2* __restrict__ pairs) {
    int e = blockIdx.x * 256 + threadIdx.x;
    if (e >= N_EDGES) return;
    int c = ei[N_EDGES + e];
    int pos = rowp[c] + rank[e];
    pairs[pos] = make_int2(ei[e], __float_as_int(ew[e]));
}

// per-node: deg = sum of row weights; dis = rsqrt(deg) or 0. No atomics.
__global__ void deg_dis_kernel(const int* __restrict__ rowp,
                               const int2* __restrict__ pairs,
                               float* __restrict__ dis) {
    int v = blockIdx.x * 256 + threadIdx.x;
    if (v >= N_NODES) return;
    int b = rowp[v], e = rowp[v + 1];
    float d = 0.f;
    for (int j = b; j < e; ++j) d += __int_as_float(pairs[j].y);
    dis[v] = d > 0.f ? rsqrtf(d) : 0.f;
}

// ---------------------------------------------------------------------------
// Fused prep: xb = bf16(x); W1F/W2F = fragment-ordered bf16 weights.
// Fragment order: short index = ((((nh*2+wc)*4+ks)*4+nt)*64+lane)*8 + j
// so a wave's wf[nt] load is one coalesced dwordx4 at base + lane*16.
// Phase A (W1F): value = W1[kk][row], row = nh*128+wc*64+nt*16+fr,
//                kk = ks*32+fq*8+j.          (W1 is [128][256])
// Phase B (W2F): value = W2[kk][n],  n = wc*64+nt*16+fr,
//                kk = nh*128+ks*32+fq*8+j.   (W2 is [256][128])
// ---------------------------------------------------------------------------
__global__ void prep_kernel(const float* __restrict__ x, uint32_t* __restrict__ xb,
                            const float* __restrict__ W1, unsigned short* __restrict__ W1F,
                            const float* __restrict__ W2, unsigned short* __restrict__ W2F) {
    int b = blockIdx.x;
    if (b < 12500) {                                   // 12500*256*4 = 100000*128
        int i = b * 256 + threadIdx.x;
        float4 v = ((const float4*)x)[i];
        uint32_t lo = (uint32_t)f32_to_bf16(v.x) | ((uint32_t)f32_to_bf16(v.y) << 16);
        uint32_t hi = (uint32_t)f32_to_bf16(v.z) | ((uint32_t)f32_to_bf16(v.w) << 16);
        ((uint2*)xb)[i] = make_uint2(lo, hi);
    } else if (b < 12628) {                            // W1F: 32768 shorts
        int idx = (b - 12500) * 256 + threadIdx.x;
        int j = idx & 7, lane = (idx >> 3) & 63;
        int nt = (idx >> 9) & 3, ks = (idx >> 11) & 3;
        int wc = (idx >> 13) & 1, nh = (idx >> 14) & 1;
        int fr = lane & 15, fq = lane >> 4;
        int row = nh * 128 + wc * 64 + nt * 16 + fr;
        int kk = ks * 32 + fq * 8 + j;
        W1F[idx] = f32_to_bf16(W1[kk * HID_DIM + row]);
    } else {                                           // W2F: 32768 shorts
        int idx = (b - 12628) * 256 + threadIdx.x;
        int j = idx & 7, lane = (idx >> 3) & 63;
        int nt = (idx >> 9) & 3, ks = (idx >> 11) & 3;
        int wc = (idx >> 13) & 1, nh = (idx >> 14) & 1;
        int fr = lane & 15, fq = lane >> 4;
        int n = wc * 64 + nt * 16 + fr;
        int kk = nh * 128 + ks * 32 + fq * 8 + j;
        W2F[idx] = f32_to_bf16(W2[kk * OUT_DIM + n]);
    }
}

// ---------------------------------------------------------------------------
// Aggregation: 2 nodes per wave (32 lanes/node, uint2 = 4 bf16 dims per lane).
// out[v] = sum_e (w*dis[src]*dis[v]) * feat[src]  (+bias). Unroll 4/2/1.
// ---------------------------------------------------------------------------
template <bool OUT_BF16>
__global__ void aggregate_kernel(const uint2* __restrict__ feat,
                                 const int* __restrict__ rowp,
                                 const int2* __restrict__ pairs,
                                 const float* __restrict__ dis,
                                 void* __restrict__ out_v,
                                 const float* __restrict__ bias) {
    int gtid = blockIdx.x * blockDim.x + threadIdx.x;
    int node = gtid >> 5;
    int lane = threadIdx.x & 31;
    if (node >= N_NODES) return;
    int beg = rowp[node], end = rowp[node + 1];
    float dv = dis[node];
    float ax = 0.f, ay = 0.f, az = 0.f, aw = 0.f;

    int j = beg;
    for (; j + 4 <= end; j += 4) {
        int2 p[4]; uint2 u[4]; float d[4];
        #pragma unroll
        for (int q = 0; q < 4; ++q) p[q] = pairs[j + q];
        #pragma unroll
        for (int q = 0; q < 4; ++q) {
            u[q] = feat[(size_t)p[q].x * 32 + lane];
            d[q] = dis[p[q].x];
        }
        #pragma unroll
        for (int q = 0; q < 4; ++q) {
            float w = __int_as_float(p[q].y) * d[q] * dv;
            ax += w * bf16_lo(u[q].x); ay += w * bf16_hi(u[q].x);
            az += w * bf16_lo(u[q].y); aw += w * bf16_hi(u[q].y);
        }
    }
    if (j + 2 <= end) {
        int2 p0 = pairs[j], p1 = pairs[j + 1];
        uint2 u0 = feat[(size_t)p0.x * 32 + lane];
        uint2 u1 = feat[(size_t)p1.x * 32 + lane];
        float w0 = __int_as_float(p0.y) * dis[p0.x] * dv;
        float w1 = __int_as_float(p1.y) * dis[p1.x] * dv;
        ax += w0 * bf16_lo(u0.x) + w1 * bf16_lo(u1.x);
        ay += w0 * bf16_hi(u0.x) + w1 * bf16_hi(u1.x);
        az += w0 * bf16_lo(u0.y) + w1 * bf16_lo(u1.y);
        aw += w0 * bf16_hi(u0.y) + w1 * bf16_hi(u1.y);
        j += 2;
    }
    if (j < end) {
        int2 p0 = pairs[j];
        uint2 u0 = feat[(size_t)p0.x * 32 + lane];
        float w0 = __int_as_float(p0.y) * dis[p0.x] * dv;
        ax += w0 * bf16_lo(u0.x); ay += w0 * bf16_hi(u0.x);
        az += w0 * bf16_lo(u0.y); aw += w0 * bf16_hi(u0.y);
    }
    if (bias) {
        float4 b = ((const float4*)bias)[lane];
        ax += b.x; ay += b.y; az += b.z; aw += b.w;
    }
    if (OUT_BF16) {
        uint2 o;
        o.x = (uint32_t)f32_to_bf16(ax) | ((uint32_t)f32_to_bf16(ay) << 16);
        o.y = (uint32_t)f32_to_bf16(az) | ((uint32_t)f32_to_bf16(aw) << 16);
        ((uint2*)out_v)[(size_t)node * 32 + lane] = o;
    } else {
        ((float4*)out_v)[(size_t)node * 32 + lane] = make_float4(ax, ay, az, aw);
    }
}

// ---------------------------------------------------------------------------
// Fused 2-layer GEMM: T = relu(A @ W1 + b1) @ W2, bf16 in/out, fp32 acc.
// R7: (1) W streams are fragment-ordered (W1F/W2F) -> every wf load is one
// coalesced global_load_dwordx4 (base + lane*16), prefetchable by the unroll;
// previously each was a 16-cache-line gather on the critical path (MfmaUtil
// 10%). (2) A-fragments hoisted to registers once (af[4][4]) and reused by
// both nh halves. LDS 66KB -> 2 blocks/CU; launch_bounds(256,2) gives the
// allocator the full 256-VGPR budget (no spills).
// ---------------------------------------------------------------------------
__global__ __launch_bounds__(256, 2) void gemm_fused_kernel(
    const unsigned short* __restrict__ A,     // [M][128] bf16
    const unsigned short* __restrict__ W1F,   // frag-ordered, 32768 shorts
    const float* __restrict__ b1,             // [256]
    const unsigned short* __restrict__ W2F,   // frag-ordered, 32768 shorts
    unsigned short* __restrict__ T,           // [M][128] bf16
    int M) {
    __shared__ unsigned short As[128 * 128];  // 32KB, chunk-swizzled
    __shared__ unsigned short Hs[128 * 136];  // 34KB, padded rows
    int tid = threadIdx.x;
    int wave = tid >> 6, lane = tid & 63;
    int m0 = blockIdx.x * 128;
    int wr = (wave & 1) * 64;
    int wcid = wave >> 1;
    int wc = wcid * 64;
    int fr = lane & 15, fq = lane >> 4;

    // stage A block: 2048 16B-chunks, 8 rounds of 256 lanes (XOR-swizzled)
    #pragma unroll
    for (int i = 0; i < 8; ++i) {
        int cbase = (i * 4 + wave) * 64;
        int c = cbase + lane;
        int m = c >> 4, cl = c & 15;
        int qg = ((cl & 7) ^ (m & 7)) | (cl & 8);
        int gm = m0 + m; if (gm >= M) gm = M - 1;
        const unsigned short* ga = A + (size_t)gm * 128 + qg * 8;
        __builtin_amdgcn_global_load_lds(
            (const __attribute__((address_space(1))) void*)ga,
            (__attribute__((address_space(3))) void*)(As + (size_t)cbase * 8),
            16, 0, 0);
    }
    __syncthreads();

    // A fragments to registers once; reused by both nh halves.
    bf16x8 af[4][4];   // [ks][mt]
    #pragma unroll
    for (int ks = 0; ks < 4; ++ks) {
        int q = ks * 4 + fq;
        int cl = ((q & 7) ^ (fr & 7)) | (q & 8);
        #pragma unroll
        for (int mt = 0; mt < 4; ++mt)
            af[ks][mt] = *(const bf16x8*)(As + (wr + mt * 16 + fr) * 128 + cl * 8);
    }

    const bf16x8* w1p = (const bf16x8*)W1F;
    const bf16x8* w2p = (const bf16x8*)W2F;

    f32x4 acc_t[4][4] = {};
    #pragma unroll
    for (int nh = 0; nh < 2; ++nh) {
        int wbase = (nh * 2 + wcid) * 16 * 64;   // 16 frags x 64 lanes per (nh,wc)
        // phase A: acc_h = A_tile @ W1[nh half]
        f32x4 acc_h[4][4] = {};
        #pragma unroll
        for (int ks = 0; ks < 4; ++ks) {
            bf16x8 wf[4];
            #pragma unroll
            for (int nt = 0; nt < 4; ++nt)
                wf[nt] = w1p[wbase + (ks * 4 + nt) * 64 + lane];
            #pragma unroll
            for (int mt = 0; mt < 4; ++mt)
                #pragma unroll
                for (int nt = 0; nt < 4; ++nt)
                    acc_h[mt][nt] = __builtin_amdgcn_mfma_f32_16x16x32_bf16(
                        af[ks][mt], wf[nt], acc_h[mt][nt], 0, 0, 0);
        }
        float bv[4];
        #pragma unroll
        for (int nt = 0; nt < 4; ++nt) bv[nt] = b1[nh * 128 + wc + nt * 16 + fr];
        __syncthreads();   // prior half's Hs consumers done
        #pragma unroll
        for (int mt = 0; mt < 4; ++mt)
            #pragma unroll
            for (int r = 0; r < 4; ++r) {
                int row = wr + mt * 16 + fq * 4 + r;
                #pragma unroll
                for (int nt = 0; nt < 4; ++nt) {
                    float v = fmaxf(acc_h[mt][nt][r] + bv[nt], 0.f);
                    Hs[row * 136 + wc + nt * 16 + fr] = f32_to_bf16(v);
                }
            }
        __syncthreads();   // Hs ready
        // phase B: acc_t += Hs @ W2[nh half rows]
        #pragma unroll
        for (int ks = 0; ks < 4; ++ks) {
            bf16x8 wf[4], hf[4];
            #pragma unroll
            for (int nt = 0; nt < 4; ++nt)
                wf[nt] = w2p[wbase + (ks * 4 + nt) * 64 + lane];
            #pragma unroll
            for (int mt = 0; mt < 4; ++mt)
                hf[mt] = *(const bf16x8*)(Hs + (wr + mt * 16 + fr) * 136 + ks * 32 + fq * 8);
            #pragma unroll
            for (int mt = 0; mt < 4; ++mt)
                #pragma unroll
                for (int nt = 0; nt < 4; ++nt)
                    acc_t[mt][nt] = __builtin_amdgcn_mfma_f32_16x16x32_bf16(
                        hf[mt], wf[nt], acc_t[mt][nt], 0, 0, 0);
        }
    }

    // epilogue: C/D layout col=lane&15, row=(lane>>4)*4+reg (m89-verified)
    #pragma unroll
    for (int mt = 0; mt < 4; ++mt)
        #pragma unroll
        for (int r = 0; r < 4; ++r) {
            int row = m0 + wr + mt * 16 + fq * 4 + r;
            if (row >= M) continue;
            #pragma unroll
            for (int nt = 0; nt < 4; ++nt)
                T[(size_t)row * 128 + wc + nt * 16 + fr] = f32_to_bf16(acc_t[mt][nt][r]);
        }
}

// ---------------------------------------------------------------------------
extern "C" void kernel_launch(void* const* d_in, const int* in_sizes, int n_in,
                              void* d_out, int out_size, void* d_ws, size_t ws_size,
                              hipStream_t stream) {
    const float* x  = (const float*)d_in[0];
    const int*   ei = (const int*)d_in[1];    // int32 (harness converts ints)
    const float* ew = (const float*)d_in[2];
    const float* W1 = (const float*)d_in[3];
    const float* b1 = (const float*)d_in[4];
    const float* W2 = (const float*)d_in[5];
    const float* b2 = (const float*)d_in[6];
    float* out = (float*)d_out;

    char* ws = (char*)d_ws;
    size_t off = 0;
    auto alloc = [&](size_t bytes) -> void* {
        void* p = ws + off;
        off = (off + bytes + 255) & ~(size_t)255;
        return p;
    };
    int*   cnt   = (int*)  alloc((size_t)N_NODES * 4);
    float* dis   = (float*)alloc((size_t)N_NODES * 4);
    int*   rowp  = (int*)  alloc((size_t)(N_NODES + 1) * 4);
    int*   bsums = (int*)  alloc(512 * 4);
    int*   rank  = (int*)  alloc((size_t)N_EDGES * 4);
    int2*  pairs = (int2*) alloc((size_t)N_EDGES * 8);
    uint32_t* xb = (uint32_t*)alloc((size_t)N_NODES * IN_DIM * 2);
    unsigned short* W1F = (unsigned short*)alloc((size_t)IN_DIM * HID_DIM * 2);
    unsigned short* W2F = (unsigned short*)alloc((size_t)HID_DIM * OUT_DIM * 2);
    unsigned short* A1  = (unsigned short*)alloc((size_t)N_NODES * IN_DIM * 2);
    unsigned short* t   = (unsigned short*)alloc((size_t)N_NODES * OUT_DIM * 2);

    hipMemsetAsync(cnt, 0, (size_t)N_NODES * 4, stream);

    int ne_blocks = (N_EDGES + 255) / 256;
    int nn_blocks = (N_NODES + 255) / 256;   // 391

    rank_hist_kernel<<<ne_blocks, 256, 0, stream>>>(ei, cnt, rank);
    scan1_kernel<<<nn_blocks, 256, 0, stream>>>(cnt, rowp, bsums, N_NODES);
    scan2_kernel<<<1, 512, 0, stream>>>(bsums, nn_blocks);
    scan3_kernel<<<nn_blocks, 256, 0, stream>>>(rowp, bsums, N_NODES, N_EDGES);
    place_kernel<<<ne_blocks, 256, 0, stream>>>(ei, ew, rank, rowp, pairs);
    deg_dis_kernel<<<nn_blocks, 256, 0, stream>>>(rowp, pairs, dis);
    prep_kernel<<<12756, 256, 0, stream>>>(x, xb, W1, W1F, W2, W2F);

    int agg_blocks = (N_NODES * 32) / 256;   // 12500, exact

    // layer 1 aggregate: A1 = agg(xb) [bf16]
    aggregate_kernel<true><<<agg_blocks, 256, 0, stream>>>(
        (const uint2*)xb, rowp, pairs, dis, A1, nullptr);

    // fused dense stack: t = relu(A1 @ W1 + b1) @ W2  [bf16]
    gemm_fused_kernel<<<(N_NODES + 127) / 128, 256, 0, stream>>>(
        A1, W1F, b1, W2F, t, N_NODES);

    // layer 2 aggregate: out = agg(t) + b2 [fp32]
    aggregate_kernel<false><<<agg_blocks, 256, 0, stream>>>(
        (const uint2*)t, rowp, pairs, dis, out, b2);
}